// Round 13
// baseline (164.709 us; speedup 1.0000x reference)
//
#include <hip/hip_runtime.h>
#include <math.h>

#define NPTS 4096
#define NB 2
#define BIGNEG -3.0e38f

typedef __attribute__((ext_vector_type(8))) short short8;
typedef __attribute__((ext_vector_type(4))) float f32x4;
typedef unsigned int uint32;

__device__ __forceinline__ unsigned short f2bf(float f) {
  uint32 u = __float_as_uint(f);
  uint32 r = (u + 0x7FFFu + ((u >> 16) & 1u)) >> 16;
  return (unsigned short)r;
}
__device__ __forceinline__ uint2 pack4(float a, float b, float c, float d) {
  uint2 r;
  r.x = (uint32)f2bf(a) | ((uint32)f2bf(b) << 16);
  r.y = (uint32)f2bf(c) | ((uint32)f2bf(d) << 16);
  return r;
}
// truncation-pack: result = hi16(hi) << 16 | hi16(lo)  (1 v_perm_b32)
__device__ __forceinline__ uint32 packtr(float lo, float hi) {
  return __builtin_amdgcn_perm(__float_as_uint(hi), __float_as_uint(lo), 0x07060302u);
}
__device__ __forceinline__ float bflo(uint32 w) { return __uint_as_float((w & 0xffffu) << 16); }
__device__ __forceinline__ float bfhi(uint32 w) { return __uint_as_float(w & 0xffff0000u); }

// ==================== prep + maxd2 (merged; proven) ====================
struct PrepP {
  const float *h2, *h1, *pc;
  const float* wsrc[6];
  unsigned short* wdst[6];
  unsigned short *h2t, *Zt;
  unsigned int* mx;
};

union ShPrep {
  float tile[64][65];
  struct { float4 sp[512]; float lm[8]; } m;
};

__global__ __launch_bounds__(256)
void prep_maxd2(PrepP P) {
  __shared__ ShPrep sh;
  int bid = blockIdx.x, tid = threadIdx.x;
  if (bid < 2304) {
    const float* src; unsigned short* dst; int S, C, b, c0, n0;
    if (bid < 2048) {
      b = bid >> 10; int r = bid & 1023;
      c0 = (r & 15) * 64; n0 = (r >> 4) * 64;
      src = P.h2; dst = P.h2t; S = 1024; C = 1024;
    } else {
      int r = bid - 2048; b = r >> 7; int r2 = r & 127;
      c0 = (r2 & 1) * 64; n0 = (r2 >> 1) * 64;
      src = P.h1; dst = P.Zt; S = 192; C = 128;
    }
    const float* sb = src + (size_t)b * C * NPTS;
#pragma unroll
    for (int p = 0; p < 4; ++p) {
      int r = (tid >> 4) + p * 16, q = tid & 15;
      float4 v = *(const float4*)(sb + (size_t)(c0 + r) * NPTS + n0 + q * 4);
      sh.tile[r][q * 4 + 0] = v.x;
      sh.tile[r][q * 4 + 1] = v.y;
      sh.tile[r][q * 4 + 2] = v.z;
      sh.tile[r][q * 4 + 3] = v.w;
    }
    __syncthreads();
#pragma unroll
    for (int p = 0; p < 2; ++p) {
      int n = (tid >> 3) + p * 32, j = tid & 7;
      uint2 lo = pack4(sh.tile[j * 8 + 0][n], sh.tile[j * 8 + 1][n], sh.tile[j * 8 + 2][n],
                       sh.tile[j * 8 + 3][n]);
      uint2 hi = pack4(sh.tile[j * 8 + 4][n], sh.tile[j * 8 + 5][n], sh.tile[j * 8 + 6][n],
                       sh.tile[j * 8 + 7][n]);
      *(uint4*)(dst + ((size_t)b * NPTS + n0 + n) * S + c0 + j * 8) =
          make_uint4(lo.x, lo.y, hi.x, hi.y);
    }
  } else if (bid < 2336) {
    int r = bid - 2304;
    for (int idx = r * 256 + tid; idx < NB * NPTS * 7; idx += 32 * 256) {
      int u = idx % 7, n = (idx / 7) & (NPTS - 1), b = idx / (7 * NPTS);
      *(uint2*)(P.Zt + ((size_t)b * NPTS + n) * 192 + 164 + u * 4) = make_uint2(0u, 0u);
    }
  } else if (bid < 2592) {
    const int segKp[6] = {1024, 256, 64, 192, 512, 256};
    const int segM[6] = {256, 64, 32, 512, 256, 128};
    const int segK[6] = {1024, 256, 64, 164, 512, 256};
    const int segEnd[6] = {262144, 278528, 282624, 380928, 512000, 544768};
    int r = bid - 2336;
    for (int idx = r * 256 + tid; idx < 544768; idx += 256 * 256) {
      int w = 0, start = 0;
#pragma unroll
      for (int s = 0; s < 6; ++s)
        if (idx >= segEnd[s]) { w = s + 1; start = segEnd[s]; }
      int local = idx - start, Kp = segKp[w], m = local / Kp, k = local % Kp;
      float v = (m < segM[w] && k < segK[w]) ? P.wsrc[w][m * segK[w] + k] : 0.f;
      P.wdst[w][local] = f2bf(v);
    }
  } else {
    // maxd2: one 64i x 512j tile
    int vb = bid - 2592;
    int b = vb >> 9, rem = vb & 511, it = rem & 63, jt = rem >> 6;
    int i0 = it * 64, j0 = jt * 512;
    const float* pb = P.pc + (size_t)b * NPTS * 3;
    for (int t = tid; t < 512; t += 256) {
      int j = j0 + t;
      float x = pb[j * 3], y = pb[j * 3 + 1], z = pb[j * 3 + 2];
      sh.m.sp[t] = make_float4(x, y, z, fmaf(x, x, fmaf(y, y, z * z)));
    }
    __syncthreads();
    int il = tid & 63, sl = tid >> 6;
    int i = i0 + il;
    float xi = pb[i * 3], yi = pb[i * 3 + 1], zi = pb[i * 3 + 2];
    float x2i = fmaf(xi, xi, fmaf(yi, yi, zi * zi));
    float m = 0.f;
#pragma unroll 4
    for (int j = sl * 128, e2 = sl * 128 + 128; j < e2; ++j) {
      float4 pj = sh.m.sp[j];
      float dot = fmaf(xi, pj.x, fmaf(yi, pj.y, zi * pj.z));
      m = fmaxf(m, fmaf(-2.f, dot, x2i + pj.w));
    }
#pragma unroll
    for (int off = 32; off > 0; off >>= 1) m = fmaxf(m, __shfl_xor(m, off, 64));
    if ((tid & 63) == 0) sh.m.lm[tid >> 6] = m;
    __syncthreads();
    if (tid == 0) {
      float v = fmaxf(fmaxf(sh.m.lm[0], sh.m.lm[1]), fmaxf(sh.m.lm[2], sh.m.lm[3]));
      atomicMax(&P.mx[b], __float_as_uint(v));
    }
  }
}

// ==================== GEMM (+ co-scheduled eig) with consumer-side BN finalize =======
// BN_IN=1: pre-phase reduces psIn/pqIn (previous dispatch's partials; kernel-boundary
// coherent) into LDS a/b/f for channels [chOff, chOff+nch); identity elsewhere.
struct GemmP {
  const unsigned short* Wp;
  const unsigned short* X;
  const float *psIn, *pqIn, *gam, *bet;
  int chOff, nch;
  unsigned short* Y;
  int Ystride;
  float *psO, *pqO;
  int M, Kp;
};
struct EigP {
  const float* pc;
  const unsigned int* mx;
  float* part;
  const float *ew1, *eb1, *ew2, *eb2;
  unsigned short* Zt;
};

union ShG {
  struct { char db[2][18432]; float ash[512], bsh[512], fsh[512]; } g;
  struct { float4 sp[1024]; float red[4][32][10]; } e;
};

template <int BN_IN, int EIG>
__global__ __launch_bounds__(256)
void gemm_k(GemmP P, EigP E) {
  __shared__ ShG sh;
  const int tid = threadIdx.x;

  if (EIG == 1 && blockIdx.z >= NB) {
    // ---- eigs_partial: one 32i x 1024j tile ----
    int e = blockIdx.x + 32 * blockIdx.y + 128 * (blockIdx.z - NB);
    int b = e >> 9, rem = e & 511, it = rem & 127, js = rem >> 7;
    int i0 = it * 32, j0 = js * 1024;
    const float* pb = E.pc + (size_t)b * NPTS * 3;
    for (int t = tid; t < 1024; t += 256) {
      int j = j0 + t;
      float x = pb[j * 3], y = pb[j * 3 + 1], z = pb[j * 3 + 2];
      sh.e.sp[t] = make_float4(x, y, z, fmaf(x, x, fmaf(y, y, z * z)));
    }
    __syncthreads();
    int il = tid & 31, sl = tid >> 5;
    int i = i0 + il;
    float xi = pb[i * 3], yi = pb[i * 3 + 1], zi = pb[i * 3 + 2];
    float x2i = fmaf(xi, xi, fmaf(yi, yi, zi * zi));
    float r2 = 0.01f * fmaxf(__uint_as_float(E.mx[b]), 1e-12f);
    float v0 = 0, v1 = 0, v2 = 0, v3 = 0, v4 = 0, v5 = 0, v6 = 0, v7 = 0, v8 = 0, v9 = 0;
#pragma unroll 2
    for (int j = sl * 128, e2 = sl * 128 + 128; j < e2; ++j) {
      float4 pj = sh.e.sp[j];
      float dot = fmaf(xi, pj.x, fmaf(yi, pj.y, zi * pj.z));
      float d2 = fmaf(-2.f, dot, x2i + pj.w);
      float msk = d2 < r2 ? 1.f : 0.f;
      float qx = msk * pj.x, qy = msk * pj.y, qz = msk * pj.z;
      v0 += msk; v1 += qx; v2 += qy; v3 += qz;
      v4 = fmaf(qx, pj.x, v4); v5 = fmaf(qx, pj.y, v5); v6 = fmaf(qx, pj.z, v6);
      v7 = fmaf(qy, pj.y, v7); v8 = fmaf(qy, pj.z, v8); v9 = fmaf(qz, pj.z, v9);
    }
    int iloc = i - j0;
    if (iloc >= sl * 128 && iloc < sl * 128 + 128) {
      v0 -= 1.f; v1 -= xi; v2 -= yi; v3 -= zi;
      v4 = fmaf(-xi, xi, v4); v5 = fmaf(-xi, yi, v5); v6 = fmaf(-xi, zi, v6);
      v7 = fmaf(-yi, yi, v7); v8 = fmaf(-yi, zi, v8); v9 = fmaf(-zi, zi, v9);
    }
    float vals[10] = {v0, v1, v2, v3, v4, v5, v6, v7, v8, v9};
#pragma unroll
    for (int v = 0; v < 10; ++v) vals[v] += __shfl_xor(vals[v], 32, 64);
    int w = tid >> 6;
    if ((tid & 63) < 32)
#pragma unroll
      for (int v = 0; v < 10; ++v) sh.e.red[w][il][v] = vals[v];
    __syncthreads();
    if (tid < 32) {
      int ii = i0 + tid;
      size_t base = ((size_t)(b * 4 + js) * 10) * NPTS + ii;
#pragma unroll
      for (int v = 0; v < 10; ++v)
        E.part[base + (size_t)v * NPTS] =
            sh.e.red[0][tid][v] + sh.e.red[1][tid][v] + sh.e.red[2][tid][v] +
            sh.e.red[3][tid][v];
    }
    return;
  }

  if (EIG == 2 && blockIdx.z >= NB) {
    // ---- eigs_finalize ----
    int p = blockIdx.x * 256 + tid;
    int b = p >> 12, i = p & (NPTS - 1);
    float t[10];
#pragma unroll
    for (int v = 0; v < 10; ++v) {
      float s = 0.f;
#pragma unroll
      for (int js = 0; js < 4; ++js)
        s += E.part[((size_t)(b * 4 + js) * 10 + v) * NPTS + i];
      t[v] = s;
    }
    double cntd = (double)t[0];
    double denom = cntd > 1.0 ? cntd : 1.0;
    double mux = t[1] / denom, muy = t[2] / denom, muz = t[3] / denom;
    const double inv_n = 1.0 / (double)NPTS;
    double a00 = ((double)t[4] - cntd * mux * mux) * inv_n;
    double a01 = ((double)t[5] - cntd * mux * muy) * inv_n;
    double a02 = ((double)t[6] - cntd * mux * muz) * inv_n;
    double a11 = ((double)t[7] - cntd * muy * muy) * inv_n;
    double a12 = ((double)t[8] - cntd * muy * muz) * inv_n;
    double a22 = ((double)t[9] - cntd * muz * muz) * inv_n;
    double e0, e1, e2;
    double p1 = a01 * a01 + a02 * a02 + a12 * a12;
    double q = (a00 + a11 + a22) / 3.0;
    double d0 = a00 - q, d1 = a11 - q, d2q = a22 - q;
    double p2 = d0 * d0 + d1 * d1 + d2q * d2q + 2.0 * p1;
    if (p2 <= 1e-30) {
      e0 = e1 = e2 = q;
    } else {
      double pp = sqrt(p2 / 6.0);
      double ip = 1.0 / pp;
      double b00 = d0 * ip, b11 = d1 * ip, b22 = d2q * ip;
      double b01 = a01 * ip, b02 = a02 * ip, b12 = a12 * ip;
      double detB = b00 * (b11 * b22 - b12 * b12) - b01 * (b01 * b22 - b12 * b02) +
                    b02 * (b01 * b12 - b11 * b02);
      double r = detB * 0.5;
      r = r < -1.0 ? -1.0 : (r > 1.0 ? 1.0 : r);
      double phi = acos(r) / 3.0;
      e2 = q + 2.0 * pp * cos(phi);
      e0 = q + 2.0 * pp * cos(phi + 2.0943951023931953);
      e1 = 3.0 * q - e0 - e2;
    }
    float eg[3] = {(float)e0, (float)e1, (float)e2};
    float tmp[4];
#pragma unroll
    for (int e = 0; e < 4; ++e) {
      float v = E.eb1[e];
#pragma unroll
      for (int k = 0; k < 3; ++k) v = fmaf(eg[k], E.ew1[k * 4 + e], v);
      tmp[e] = fmaxf(v, 0.f);
    }
    float h3[4];
#pragma unroll
    for (int f = 0; f < 4; ++f) {
      float v = E.eb2[f];
#pragma unroll
      for (int e = 0; e < 4; ++e) v = fmaf(tmp[e], E.ew2[e * 4 + f], v);
      h3[f] = v;
    }
    *(uint2*)(E.Zt + ((size_t)b * NPTS + i) * 192 + 160) = pack4(h3[0], h3[1], h3[2], h3[3]);
    return;
  }

  // ---- GEMM: 64M x 128N tiles, BK=64, 4 waves; 2-deep reg pipeline ----
  const int b = blockIdx.z, nt = blockIdx.x, mt = blockIdx.y;
  const int n0 = nt * 128, m0 = mt * 64;
  const int lane = tid & 63, wid = tid >> 6;
  const int wm = wid >> 1, wn = wid & 1, g = lane >> 4, c = lane & 15;
  const int kt = P.Kp >> 6;
  const unsigned short* Xb = P.X + (size_t)b * NPTS * P.Kp;

  if (BN_IN) {
    // pre-phase: identity defaults, then in-block BN finalize for [chOff, chOff+nch)
    for (int ch = tid; ch < P.Kp; ch += 256) {
      sh.g.ash[ch] = 1.f;
      sh.g.bsh[ch] = 0.f;
      sh.g.fsh[ch] = BIGNEG;
    }
    __syncthreads();
    for (int idx = tid; idx < P.nch; idx += 256) {
      const float4* s4 = (const float4*)(P.psIn + (size_t)idx * 128);
      const float4* q4 = (const float4*)(P.pqIn + (size_t)idx * 128);
      float s = 0.f, q = 0.f;
#pragma unroll 8
      for (int i = 0; i < 32; ++i) {
        float4 a = s4[i];
        s += a.x + a.y + a.z + a.w;
        float4 w = q4[i];
        q += w.x + w.y + w.z + w.w;
      }
      const float inv = 1.f / 8192.f;
      float mean = s * inv;
      float var = fmaxf(q * inv - mean * mean, 0.f);
      float aa = rsqrtf(var + 1e-5f) * P.gam[idx];
      int ch = P.chOff + idx;
      sh.g.ash[ch] = aa;
      sh.g.bsh[ch] = P.bet[idx] - mean * aa;
      sh.g.fsh[ch] = 0.f;
    }
    __syncthreads();
  }

  uint4 R0[4], R1[4];
  auto loadG = [&](int t, uint4* R) {
    int k0 = t << 6;
#pragma unroll
    for (int i = 0; i < 4; ++i) {
      int u = tid + i * 256, n = u >> 3, s = u & 7;
      R[i] = *(const uint4*)(Xb + (size_t)(n0 + n) * P.Kp + k0 + s * 8);
    }
  };
  auto writeS = [&](int buf, int t, uint4* R) {
    int k0 = t << 6;
#pragma unroll
    for (int i = 0; i < 4; ++i) {
      int u = tid + i * 256, s = u & 7;
      uint4 v = R[i];
      if (BN_IN) {
        int k = k0 + s * 8;
        float4 a0 = *(const float4*)&sh.g.ash[k], a1 = *(const float4*)&sh.g.ash[k + 4];
        float4 b0 = *(const float4*)&sh.g.bsh[k], b1 = *(const float4*)&sh.g.bsh[k + 4];
        float4 f0 = *(const float4*)&sh.g.fsh[k], f1 = *(const float4*)&sh.g.fsh[k + 4];
        float e0 = fmaxf(fmaf(bflo(v.x), a0.x, b0.x), f0.x);
        float e1 = fmaxf(fmaf(bfhi(v.x), a0.y, b0.y), f0.y);
        float e2 = fmaxf(fmaf(bflo(v.y), a0.z, b0.z), f0.z);
        float e3 = fmaxf(fmaf(bfhi(v.y), a0.w, b0.w), f0.w);
        float e4 = fmaxf(fmaf(bflo(v.z), a1.x, b1.x), f1.x);
        float e5 = fmaxf(fmaf(bfhi(v.z), a1.y, b1.y), f1.y);
        float e6 = fmaxf(fmaf(bflo(v.w), a1.z, b1.z), f1.z);
        float e7 = fmaxf(fmaf(bfhi(v.w), a1.w, b1.w), f1.w);
        v.x = packtr(e0, e1);
        v.y = packtr(e2, e3);
        v.z = packtr(e4, e5);
        v.w = packtr(e6, e7);
      }
      *(uint4*)&sh.g.db[buf][(u >> 3) * 144 + (u & 7) * 16] = v;
    }
  };
  auto loadA = [&](int t, uint4* Af) {
    const unsigned short* base = P.Wp + (size_t)(m0 + wm * 32 + c) * P.Kp + (t << 6) + g * 8;
#pragma unroll
    for (int mf = 0; mf < 2; ++mf)
#pragma unroll
      for (int kw = 0; kw < 2; ++kw)
        Af[mf * 2 + kw] = *(const uint4*)(base + (size_t)mf * 16 * P.Kp + kw * 32);
  };

  f32x4 acc[2][4] = {};
  uint4 Acur[4], Anext[4] = {};
  loadG(0, R0);
  loadA(0, Acur);
  writeS(0, 0, R0);
  if (kt > 1) loadG(1, R1);
  __syncthreads();
  int cur = 0;

  auto step = [&](int t, uint4* Rload, uint4* Rwrite) {
    if (t + 2 < kt) loadG(t + 2, Rload);
    if (t + 1 < kt) loadA(t + 1, Anext);
#pragma unroll
    for (int kw = 0; kw < 2; ++kw) {
      union { uint4 u; short8 s; } a0, a1;
      a0.u = Acur[0 * 2 + kw];
      a1.u = Acur[1 * 2 + kw];
#pragma unroll
      for (int nf = 0; nf < 4; ++nf) {
        union { uint4 u; short8 s; } bf;
        bf.u = *(const uint4*)&sh.g.db[cur][(wn * 64 + nf * 16 + c) * 144 + kw * 64 + g * 16];
        acc[0][nf] = __builtin_amdgcn_mfma_f32_16x16x32_bf16(a0.s, bf.s, acc[0][nf], 0, 0, 0);
        acc[1][nf] = __builtin_amdgcn_mfma_f32_16x16x32_bf16(a1.s, bf.s, acc[1][nf], 0, 0, 0);
      }
    }
    if (t + 1 < kt) writeS(cur ^ 1, t + 1, Rwrite);
    __syncthreads();
    cur ^= 1;
#pragma unroll
    for (int i = 0; i < 4; ++i) Acur[i] = Anext[i];
  };
  for (int t = 0; t < kt;) {
    step(t, R0, R1);
    ++t;
    if (t >= kt) break;
    step(t, R1, R0);
    ++t;
  }

  // C-write (bf16 raw, round-to-nearest)
#pragma unroll
  for (int nf = 0; nf < 4; ++nf) {
    int n = n0 + wn * 64 + nf * 16 + c;
    unsigned short* yrow = P.Y + ((size_t)b * NPTS + n) * P.Ystride;
#pragma unroll
    for (int mf = 0; mf < 2; ++mf) {
      int mb = m0 + wm * 32 + mf * 16 + g * 4;
      if (mb < P.M)
        *(uint2*)(yrow + mb) =
            pack4(acc[mf][nf][0], acc[mf][nf][1], acc[mf][nf][2], acc[mf][nf][3]);
    }
  }
  // BN partials: slot = b*64 + nt*2 + wn (128 slots)
  int slot = b * 64 + nt * 2 + wn;
#pragma unroll
  for (int mf = 0; mf < 2; ++mf)
#pragma unroll
    for (int r = 0; r < 4; ++r) {
      float s = 0.f, q = 0.f;
#pragma unroll
      for (int nf = 0; nf < 4; ++nf) {
        float v = acc[mf][nf][r];
        s += v;
        q = fmaf(v, v, q);
      }
#pragma unroll
      for (int m = 1; m < 16; m <<= 1) {
        s += __shfl_xor(s, m, 64);
        q += __shfl_xor(q, m, 64);
      }
      int row = m0 + wm * 32 + mf * 16 + g * 4 + r;
      if (c == 0 && row < P.M) {
        P.psO[(size_t)row * 128 + slot] = s;
        P.pqO[(size_t)row * 128 + slot] = q;
      }
    }
}

// ==================== BN finalize (L6 only) ====================
__global__ __launch_bounds__(128)
void bn_finalize(const float* __restrict__ psum, const float* __restrict__ psq,
                 const float* __restrict__ gamma, const float* __restrict__ beta,
                 float* __restrict__ a_, float* __restrict__ b_) {
  int ch = blockIdx.x, t = threadIdx.x;
  float s = psum[(size_t)ch * 128 + t];
  float q = psq[(size_t)ch * 128 + t];
#pragma unroll
  for (int m = 1; m < 64; m <<= 1) {
    s += __shfl_xor(s, m, 64);
    q += __shfl_xor(q, m, 64);
  }
  __shared__ float ws[2][2];
  if ((t & 63) == 0) { ws[t >> 6][0] = s; ws[t >> 6][1] = q; }
  __syncthreads();
  if (t == 0) {
    float S = ws[0][0] + ws[1][0];
    float Q = ws[0][1] + ws[1][1];
    const float inv = 1.f / (float)(NB * NPTS);
    float mean = S * inv;
    float var = fmaxf(Q * inv - mean * mean, 0.f);
    float aa = rsqrtf(var + 1e-5f) * gamma[ch];
    a_[ch] = aa;
    b_[ch] = beta[ch] - mean * aa;
  }
}

// ==================== out: BN+transpose z + xyz copy ====================
__global__ __launch_bounds__(256)
void out_final(const unsigned short* __restrict__ Y, const float* __restrict__ a_,
               const float* __restrict__ b_, const float* __restrict__ pc,
               float* __restrict__ out) {
  int bid = blockIdx.x;
  if (bid < 1024) {
    __shared__ float tile[32][33];
    int b = bid >> 9, r0 = bid & 511;
    int c0 = (r0 & 3) * 32, n0 = (r0 >> 2) * 32;
    int r = threadIdx.x >> 3, q = threadIdx.x & 7;
    uint2 v = *(const uint2*)(Y + ((size_t)b * NPTS + n0 + r) * 128 + c0 + q * 4);
    float4 aa = *(const float4*)(a_ + c0 + q * 4);
    float4 bb = *(const float4*)(b_ + c0 + q * 4);
    tile[r][q * 4 + 0] = fmaxf(bflo(v.x) * aa.x + bb.x, 0.f);
    tile[r][q * 4 + 1] = fmaxf(bfhi(v.x) * aa.y + bb.y, 0.f);
    tile[r][q * 4 + 2] = fmaxf(bflo(v.y) * aa.z + bb.z, 0.f);
    tile[r][q * 4 + 3] = fmaxf(bfhi(v.y) * aa.w + bb.w, 0.f);
    __syncthreads();
    float4 o = make_float4(tile[q * 4 + 0][r], tile[q * 4 + 1][r], tile[q * 4 + 2][r],
                           tile[q * 4 + 3][r]);
    float* z = out + (size_t)NB * NPTS * 3;
    *(float4*)(z + ((size_t)b * 128 + c0 + r) * NPTS + n0 + q * 4) = o;
  } else {
    int i = (bid - 1024) * 256 + threadIdx.x;
    ((float4*)out)[i] = ((const float4*)pc)[i];
  }
}

extern "C" void kernel_launch(void* const* d_in, const int* in_sizes, int n_in,
                              void* d_out, int out_size, void* d_ws, size_t ws_size,
                              hipStream_t stream) {
  (void)in_sizes; (void)n_in; (void)out_size; (void)ws_size;
  const float* pc    = (const float*)d_in[0];
  const float* h1    = (const float*)d_in[1];
  const float* h2    = (const float*)d_in[2];
  const float* dgw1  = (const float*)d_in[3];
  const float* dgg1  = (const float*)d_in[5];
  const float* dgbe1 = (const float*)d_in[6];
  const float* dgw2  = (const float*)d_in[7];
  const float* dgg2  = (const float*)d_in[9];
  const float* dgbe2 = (const float*)d_in[10];
  const float* dgw3  = (const float*)d_in[11];
  const float* dgg3  = (const float*)d_in[13];
  const float* dgbe3 = (const float*)d_in[14];
  const float* ew1   = (const float*)d_in[15];
  const float* eb1   = (const float*)d_in[16];
  const float* ew2   = (const float*)d_in[17];
  const float* eb2   = (const float*)d_in[18];
  const float* w1    = (const float*)d_in[19];
  const float* g1    = (const float*)d_in[21];
  const float* be1   = (const float*)d_in[22];
  const float* w2    = (const float*)d_in[23];
  const float* g2    = (const float*)d_in[25];
  const float* be2   = (const float*)d_in[26];
  const float* w3    = (const float*)d_in[27];
  const float* g3    = (const float*)d_in[29];
  const float* be3   = (const float*)d_in[30];
  float* out = (float*)d_out;

  // ---- workspace ----
  char* p = (char*)d_ws;
  auto take = [&](size_t bytes) { char* r = p; p += (bytes + 255) & ~(size_t)255; return r; };
  unsigned int* mx = (unsigned int*)take(64);
  unsigned short* h2t = (unsigned short*)take((size_t)NB * NPTS * 1024 * 2);
  unsigned short* Zt  = (unsigned short*)take((size_t)NB * NPTS * 192 * 2);
  unsigned short* wp1 = (unsigned short*)take((size_t)256 * 1024 * 2);
  unsigned short* wp2 = (unsigned short*)take((size_t)64 * 256 * 2);
  unsigned short* wp3 = (unsigned short*)take((size_t)64 * 64 * 2);
  unsigned short* wp4 = (unsigned short*)take((size_t)512 * 192 * 2);
  unsigned short* wp5 = (unsigned short*)take((size_t)256 * 512 * 2);
  unsigned short* wp6 = (unsigned short*)take((size_t)128 * 256 * 2);
  unsigned short* yA  = (unsigned short*)take((size_t)NB * NPTS * 256 * 2);
  unsigned short* yB  = (unsigned short*)take((size_t)NB * NPTS * 512 * 2);
  float* psA = (float*)take((size_t)512 * 128 * 4);
  float* pqA = (float*)take((size_t)512 * 128 * 4);
  float* psB = (float*)take((size_t)512 * 128 * 4);
  float* pqB = (float*)take((size_t)512 * 128 * 4);
  float* a6 = (float*)take(512 * 4);
  float* b6 = (float*)take(512 * 4);
  float* part = (float*)take((size_t)NB * 4 * 10 * NPTS * 4);

  hipMemsetAsync(mx, 0, 64, stream);

  PrepP PP;
  PP.h2 = h2; PP.h1 = h1; PP.pc = pc;
  PP.wsrc[0] = dgw1; PP.wsrc[1] = dgw2; PP.wsrc[2] = dgw3;
  PP.wsrc[3] = w1;   PP.wsrc[4] = w2;   PP.wsrc[5] = w3;
  PP.wdst[0] = wp1; PP.wdst[1] = wp2; PP.wdst[2] = wp3;
  PP.wdst[3] = wp4; PP.wdst[4] = wp5; PP.wdst[5] = wp6;
  PP.h2t = h2t; PP.Zt = Zt;
  PP.mx = mx;
  prep_maxd2<<<3616, 256, 0, stream>>>(PP);

  EigP EP = {pc, mx, part, ew1, eb1, ew2, eb2, Zt};

  // L1 + eigs_partial co-scheduled -> psA
  GemmP L1 = {wp1, h2t, nullptr, nullptr, nullptr, nullptr, 0, 0,
              yA, 256, psA, pqA, 256, 1024};
  gemm_k<0, 1><<<dim3(32, 4, NB + 8), 256, 0, stream>>>(L1, EP);

  // L2 (fin L1 in pre-phase; psA) + eigs_finalize co-scheduled -> psB
  GemmP L2 = {wp2, yA, psA, pqA, dgg1, dgbe1, 0, 256,
              yB, 64, psB, pqB, 64, 256};
  gemm_k<1, 2><<<dim3(32, 1, NB + 1), 256, 0, stream>>>(L2, EP);

  // L3 (fin L2; psB) -> psA ; f2 -> Zt cols 128..159
  GemmP L3 = {wp3, yB, psB, pqB, dgg2, dgbe2, 0, 64,
              Zt + 128, 192, psA, pqA, 32, 64};
  gemm_k<1, 0><<<dim3(32, 1, NB), 256, 0, stream>>>(L3, EP);

  // L4 (fin L3; psA rows 0..31 -> channels 128..159; identity elsewhere) -> psB
  GemmP L4 = {wp4, Zt, psA, pqA, dgg3, dgbe3, 128, 32,
              yB, 512, psB, pqB, 512, 192};
  gemm_k<1, 0><<<dim3(32, 8, NB), 256, 0, stream>>>(L4, EP);

  // L5 (fin L4; psB) -> psA
  GemmP L5 = {wp5, yB, psB, pqB, g1, be1, 0, 512,
              yA, 256, psA, pqA, 256, 512};
  gemm_k<1, 0><<<dim3(32, 4, NB), 256, 0, stream>>>(L5, EP);

  // L6 (fin L5; psA) -> psB
  GemmP L6 = {wp6, yA, psA, pqA, g2, be2, 0, 256,
              yB, 128, psB, pqB, 128, 256};
  gemm_k<1, 0><<<dim3(32, 2, NB), 256, 0, stream>>>(L6, EP);

  bn_finalize<<<128, 128, 0, stream>>>(psB, pqB, g3, be3, a6, b6);
  out_final<<<1048, 256, 0, stream>>>(yB, a6, b6, pc, out);
}

// Round 14
// 139.359 us; speedup vs baseline: 1.1819x; 1.1819x over previous
//
#include <hip/hip_runtime.h>
#include <math.h>

#define NPTS 4096
#define NB 2
#define BIGNEG -3.0e38f

typedef __attribute__((ext_vector_type(8))) short short8;
typedef __attribute__((ext_vector_type(4))) float f32x4;
typedef unsigned int uint32;

__device__ __forceinline__ unsigned short f2bf(float f) {
  uint32 u = __float_as_uint(f);
  uint32 r = (u + 0x7FFFu + ((u >> 16) & 1u)) >> 16;
  return (unsigned short)r;
}
__device__ __forceinline__ uint2 pack4(float a, float b, float c, float d) {
  uint2 r;
  r.x = (uint32)f2bf(a) | ((uint32)f2bf(b) << 16);
  r.y = (uint32)f2bf(c) | ((uint32)f2bf(d) << 16);
  return r;
}
// truncation-pack: result = hi16(hi) << 16 | hi16(lo)  (1 v_perm_b32)
__device__ __forceinline__ uint32 packtr(float lo, float hi) {
  return __builtin_amdgcn_perm(__float_as_uint(hi), __float_as_uint(lo), 0x07060302u);
}
__device__ __forceinline__ float bflo(uint32 w) { return __uint_as_float((w & 0xffffu) << 16); }
__device__ __forceinline__ float bfhi(uint32 w) { return __uint_as_float(w & 0xffff0000u); }

// ==================== prep + maxd2 (merged; proven) ====================
struct PrepP {
  const float *h2, *h1, *pc;
  const float* wsrc[6];
  unsigned short* wdst[6];
  unsigned short *h2t, *Zt;
  float *aZ, *bZ, *fZ, *f0;
  unsigned int* mx;
};

union ShPrep {
  float tile[64][65];
  struct { float4 sp[512]; float lm[8]; } m;
};

__global__ __launch_bounds__(256)
void prep_maxd2(PrepP P) {
  __shared__ ShPrep sh;
  int bid = blockIdx.x, tid = threadIdx.x;
  if (bid < 2304) {
    const float* src; unsigned short* dst; int S, C, b, c0, n0;
    if (bid < 2048) {
      b = bid >> 10; int r = bid & 1023;
      c0 = (r & 15) * 64; n0 = (r >> 4) * 64;
      src = P.h2; dst = P.h2t; S = 1024; C = 1024;
    } else {
      int r = bid - 2048; b = r >> 7; int r2 = r & 127;
      c0 = (r2 & 1) * 64; n0 = (r2 >> 1) * 64;
      src = P.h1; dst = P.Zt; S = 192; C = 128;
    }
    const float* sb = src + (size_t)b * C * NPTS;
#pragma unroll
    for (int p = 0; p < 4; ++p) {
      int r = (tid >> 4) + p * 16, q = tid & 15;
      float4 v = *(const float4*)(sb + (size_t)(c0 + r) * NPTS + n0 + q * 4);
      sh.tile[r][q * 4 + 0] = v.x;
      sh.tile[r][q * 4 + 1] = v.y;
      sh.tile[r][q * 4 + 2] = v.z;
      sh.tile[r][q * 4 + 3] = v.w;
    }
    __syncthreads();
#pragma unroll
    for (int p = 0; p < 2; ++p) {
      int n = (tid >> 3) + p * 32, j = tid & 7;
      uint2 lo = pack4(sh.tile[j * 8 + 0][n], sh.tile[j * 8 + 1][n], sh.tile[j * 8 + 2][n],
                       sh.tile[j * 8 + 3][n]);
      uint2 hi = pack4(sh.tile[j * 8 + 4][n], sh.tile[j * 8 + 5][n], sh.tile[j * 8 + 6][n],
                       sh.tile[j * 8 + 7][n]);
      *(uint4*)(dst + ((size_t)b * NPTS + n0 + n) * S + c0 + j * 8) =
          make_uint4(lo.x, lo.y, hi.x, hi.y);
    }
  } else if (bid < 2336) {
    int r = bid - 2304;
    for (int idx = r * 256 + tid; idx < NB * NPTS * 7; idx += 32 * 256) {
      int u = idx % 7, n = (idx / 7) & (NPTS - 1), b = idx / (7 * NPTS);
      *(uint2*)(P.Zt + ((size_t)b * NPTS + n) * 192 + 164 + u * 4) = make_uint2(0u, 0u);
    }
  } else if (bid < 2592) {
    const int segKp[6] = {1024, 256, 64, 192, 512, 256};
    const int segM[6] = {256, 64, 32, 512, 256, 128};
    const int segK[6] = {1024, 256, 64, 164, 512, 256};
    const int segEnd[6] = {262144, 278528, 282624, 380928, 512000, 544768};
    int r = bid - 2336;
    for (int idx = r * 256 + tid; idx < 544768; idx += 256 * 256) {
      int w = 0, start = 0;
#pragma unroll
      for (int s = 0; s < 6; ++s)
        if (idx >= segEnd[s]) { w = s + 1; start = segEnd[s]; }
      int local = idx - start, Kp = segKp[w], m = local / Kp, k = local % Kp;
      float v = (m < segM[w] && k < segK[w]) ? P.wsrc[w][m * segK[w] + k] : 0.f;
      P.wdst[w][local] = f2bf(v);
    }
  } else if (bid == 2592) {
    for (int ch = tid; ch < 512; ch += 256) {
      P.f0[ch] = 0.f;
      if (ch < 192) { P.aZ[ch] = 1.f; P.bZ[ch] = 0.f; P.fZ[ch] = BIGNEG; }
    }
  } else {
    // maxd2: one 64i x 512j tile
    int vb = bid - 2593;
    int b = vb >> 9, rem = vb & 511, it = rem & 63, jt = rem >> 6;
    int i0 = it * 64, j0 = jt * 512;
    const float* pb = P.pc + (size_t)b * NPTS * 3;
    for (int t = tid; t < 512; t += 256) {
      int j = j0 + t;
      float x = pb[j * 3], y = pb[j * 3 + 1], z = pb[j * 3 + 2];
      sh.m.sp[t] = make_float4(x, y, z, fmaf(x, x, fmaf(y, y, z * z)));
    }
    __syncthreads();
    int il = tid & 63, sl = tid >> 6;
    int i = i0 + il;
    float xi = pb[i * 3], yi = pb[i * 3 + 1], zi = pb[i * 3 + 2];
    float x2i = fmaf(xi, xi, fmaf(yi, yi, zi * zi));
    float m = 0.f;
#pragma unroll 4
    for (int j = sl * 128, e2 = sl * 128 + 128; j < e2; ++j) {
      float4 pj = sh.m.sp[j];
      float dot = fmaf(xi, pj.x, fmaf(yi, pj.y, zi * pj.z));
      m = fmaxf(m, fmaf(-2.f, dot, x2i + pj.w));
    }
#pragma unroll
    for (int off = 32; off > 0; off >>= 1) m = fmaxf(m, __shfl_xor(m, off, 64));
    if ((tid & 63) == 0) sh.m.lm[tid >> 6] = m;
    __syncthreads();
    if (tid == 0) {
      float v = fmaxf(fmaxf(sh.m.lm[0], sh.m.lm[1]), fmaxf(sh.m.lm[2], sh.m.lm[3]));
      atomicMax(&P.mx[b], __float_as_uint(v));
    }
  }
}

// ==================== GEMM (+ co-scheduled eig blocks via extra z slices) ============
struct GemmP {
  const unsigned short* Wp;
  const unsigned short* X;
  const float *aIn, *bIn, *fIn;
  unsigned short* Y;
  int Ystride;
  float *psum, *psq;
  int M, Kp;
};
struct EigP {
  const float* pc;
  const unsigned int* mx;
  float* part;
  const float *ew1, *eb1, *ew2, *eb2;
  unsigned short* Zt;
};

union ShG {
  struct { char db[2][18432]; float ash[512], bsh[512], fsh[512]; } g;
  struct { float4 sp[1024]; float red[4][32][10]; } e;
};

template <int BN_IN, int EIG>
__global__ __launch_bounds__(256)
void gemm_k(GemmP P, EigP E) {
  __shared__ ShG sh;
  const int tid = threadIdx.x;

  if (EIG == 1 && blockIdx.z >= NB) {
    // ---- eigs_partial: one 32i x 1024j tile ----
    int e = blockIdx.x + 32 * blockIdx.y + 128 * (blockIdx.z - NB);
    int b = e >> 9, rem = e & 511, it = rem & 127, js = rem >> 7;
    int i0 = it * 32, j0 = js * 1024;
    const float* pb = E.pc + (size_t)b * NPTS * 3;
    for (int t = tid; t < 1024; t += 256) {
      int j = j0 + t;
      float x = pb[j * 3], y = pb[j * 3 + 1], z = pb[j * 3 + 2];
      sh.e.sp[t] = make_float4(x, y, z, fmaf(x, x, fmaf(y, y, z * z)));
    }
    __syncthreads();
    int il = tid & 31, sl = tid >> 5;
    int i = i0 + il;
    float xi = pb[i * 3], yi = pb[i * 3 + 1], zi = pb[i * 3 + 2];
    float x2i = fmaf(xi, xi, fmaf(yi, yi, zi * zi));
    float r2 = 0.01f * fmaxf(__uint_as_float(E.mx[b]), 1e-12f);
    float v0 = 0, v1 = 0, v2 = 0, v3 = 0, v4 = 0, v5 = 0, v6 = 0, v7 = 0, v8 = 0, v9 = 0;
#pragma unroll 2
    for (int j = sl * 128, e2 = sl * 128 + 128; j < e2; ++j) {
      float4 pj = sh.e.sp[j];
      float dot = fmaf(xi, pj.x, fmaf(yi, pj.y, zi * pj.z));
      float d2 = fmaf(-2.f, dot, x2i + pj.w);
      float msk = d2 < r2 ? 1.f : 0.f;
      float qx = msk * pj.x, qy = msk * pj.y, qz = msk * pj.z;
      v0 += msk; v1 += qx; v2 += qy; v3 += qz;
      v4 = fmaf(qx, pj.x, v4); v5 = fmaf(qx, pj.y, v5); v6 = fmaf(qx, pj.z, v6);
      v7 = fmaf(qy, pj.y, v7); v8 = fmaf(qy, pj.z, v8); v9 = fmaf(qz, pj.z, v9);
    }
    int iloc = i - j0;
    if (iloc >= sl * 128 && iloc < sl * 128 + 128) {
      v0 -= 1.f; v1 -= xi; v2 -= yi; v3 -= zi;
      v4 = fmaf(-xi, xi, v4); v5 = fmaf(-xi, yi, v5); v6 = fmaf(-xi, zi, v6);
      v7 = fmaf(-yi, yi, v7); v8 = fmaf(-yi, zi, v8); v9 = fmaf(-zi, zi, v9);
    }
    float vals[10] = {v0, v1, v2, v3, v4, v5, v6, v7, v8, v9};
#pragma unroll
    for (int v = 0; v < 10; ++v) vals[v] += __shfl_xor(vals[v], 32, 64);
    int w = tid >> 6;
    if ((tid & 63) < 32)
#pragma unroll
      for (int v = 0; v < 10; ++v) sh.e.red[w][il][v] = vals[v];
    __syncthreads();
    if (tid < 32) {
      int ii = i0 + tid;
      size_t base = ((size_t)(b * 4 + js) * 10) * NPTS + ii;
#pragma unroll
      for (int v = 0; v < 10; ++v)
        E.part[base + (size_t)v * NPTS] =
            sh.e.red[0][tid][v] + sh.e.red[1][tid][v] + sh.e.red[2][tid][v] +
            sh.e.red[3][tid][v];
    }
    return;
  }

  if (EIG == 2 && blockIdx.z >= NB) {
    // ---- eigs_finalize ----
    int p = blockIdx.x * 256 + tid;
    int b = p >> 12, i = p & (NPTS - 1);
    float t[10];
#pragma unroll
    for (int v = 0; v < 10; ++v) {
      float s = 0.f;
#pragma unroll
      for (int js = 0; js < 4; ++js)
        s += E.part[((size_t)(b * 4 + js) * 10 + v) * NPTS + i];
      t[v] = s;
    }
    double cntd = (double)t[0];
    double denom = cntd > 1.0 ? cntd : 1.0;
    double mux = t[1] / denom, muy = t[2] / denom, muz = t[3] / denom;
    const double inv_n = 1.0 / (double)NPTS;
    double a00 = ((double)t[4] - cntd * mux * mux) * inv_n;
    double a01 = ((double)t[5] - cntd * mux * muy) * inv_n;
    double a02 = ((double)t[6] - cntd * mux * muz) * inv_n;
    double a11 = ((double)t[7] - cntd * muy * muy) * inv_n;
    double a12 = ((double)t[8] - cntd * muy * muz) * inv_n;
    double a22 = ((double)t[9] - cntd * muz * muz) * inv_n;
    double e0, e1, e2;
    double p1 = a01 * a01 + a02 * a02 + a12 * a12;
    double q = (a00 + a11 + a22) / 3.0;
    double d0 = a00 - q, d1 = a11 - q, d2q = a22 - q;
    double p2 = d0 * d0 + d1 * d1 + d2q * d2q + 2.0 * p1;
    if (p2 <= 1e-30) {
      e0 = e1 = e2 = q;
    } else {
      double pp = sqrt(p2 / 6.0);
      double ip = 1.0 / pp;
      double b00 = d0 * ip, b11 = d1 * ip, b22 = d2q * ip;
      double b01 = a01 * ip, b02 = a02 * ip, b12 = a12 * ip;
      double detB = b00 * (b11 * b22 - b12 * b12) - b01 * (b01 * b22 - b12 * b02) +
                    b02 * (b01 * b12 - b11 * b02);
      double r = detB * 0.5;
      r = r < -1.0 ? -1.0 : (r > 1.0 ? 1.0 : r);
      double phi = acos(r) / 3.0;
      e2 = q + 2.0 * pp * cos(phi);
      e0 = q + 2.0 * pp * cos(phi + 2.0943951023931953);
      e1 = 3.0 * q - e0 - e2;
    }
    float eg[3] = {(float)e0, (float)e1, (float)e2};
    float tmp[4];
#pragma unroll
    for (int e = 0; e < 4; ++e) {
      float v = E.eb1[e];
#pragma unroll
      for (int k = 0; k < 3; ++k) v = fmaf(eg[k], E.ew1[k * 4 + e], v);
      tmp[e] = fmaxf(v, 0.f);
    }
    float h3[4];
#pragma unroll
    for (int f = 0; f < 4; ++f) {
      float v = E.eb2[f];
#pragma unroll
      for (int e = 0; e < 4; ++e) v = fmaf(tmp[e], E.ew2[e * 4 + f], v);
      h3[f] = v;
    }
    *(uint2*)(E.Zt + ((size_t)b * NPTS + i) * 192 + 160) = pack4(h3[0], h3[1], h3[2], h3[3]);
    return;
  }

  // ---- GEMM: 64M x 128N tiles, BK=64, 4 waves; 3-deep reg pipeline ----
  const int b = blockIdx.z, nt = blockIdx.x, mt = blockIdx.y;
  const int n0 = nt * 128, m0 = mt * 64;
  const int lane = tid & 63, wid = tid >> 6;
  const int wm = wid >> 1, wn = wid & 1, g = lane >> 4, c = lane & 15;
  const int kt = P.Kp >> 6;
  const unsigned short* Xb = P.X + (size_t)b * NPTS * P.Kp;

  if (BN_IN) {
    for (int ch = tid; ch < P.Kp; ch += 256) {
      sh.g.ash[ch] = P.aIn[ch];
      sh.g.bsh[ch] = P.bIn[ch];
      sh.g.fsh[ch] = P.fIn[ch];
    }
    __syncthreads();
  }

  uint4 S0[4], S1[4], S2[4];
  auto loadG = [&](int t, uint4* R) {
    int k0 = t << 6;
#pragma unroll
    for (int i = 0; i < 4; ++i) {
      int u = tid + i * 256, n = u >> 3, s = u & 7;
      R[i] = *(const uint4*)(Xb + (size_t)(n0 + n) * P.Kp + k0 + s * 8);
    }
  };
  auto writeS = [&](int buf, int t, uint4* R) {
    int k0 = t << 6;
#pragma unroll
    for (int i = 0; i < 4; ++i) {
      int u = tid + i * 256, s = u & 7;
      uint4 v = R[i];
      if (BN_IN) {
        int k = k0 + s * 8;
        float4 a0 = *(const float4*)&sh.g.ash[k], a1 = *(const float4*)&sh.g.ash[k + 4];
        float4 b0 = *(const float4*)&sh.g.bsh[k], b1 = *(const float4*)&sh.g.bsh[k + 4];
        float4 f0 = *(const float4*)&sh.g.fsh[k], f1 = *(const float4*)&sh.g.fsh[k + 4];
        float e0 = fmaxf(fmaf(bflo(v.x), a0.x, b0.x), f0.x);
        float e1 = fmaxf(fmaf(bfhi(v.x), a0.y, b0.y), f0.y);
        float e2 = fmaxf(fmaf(bflo(v.y), a0.z, b0.z), f0.z);
        float e3 = fmaxf(fmaf(bfhi(v.y), a0.w, b0.w), f0.w);
        float e4 = fmaxf(fmaf(bflo(v.z), a1.x, b1.x), f1.x);
        float e5 = fmaxf(fmaf(bfhi(v.z), a1.y, b1.y), f1.y);
        float e6 = fmaxf(fmaf(bflo(v.w), a1.z, b1.z), f1.z);
        float e7 = fmaxf(fmaf(bfhi(v.w), a1.w, b1.w), f1.w);
        v.x = packtr(e0, e1);
        v.y = packtr(e2, e3);
        v.z = packtr(e4, e5);
        v.w = packtr(e6, e7);
      }
      *(uint4*)&sh.g.db[buf][(u >> 3) * 144 + (u & 7) * 16] = v;
    }
  };
  auto loadA = [&](int t, uint4* Af) {
    const unsigned short* base = P.Wp + (size_t)(m0 + wm * 32 + c) * P.Kp + (t << 6) + g * 8;
#pragma unroll
    for (int mf = 0; mf < 2; ++mf)
#pragma unroll
      for (int kw = 0; kw < 2; ++kw)
        Af[mf * 2 + kw] = *(const uint4*)(base + (size_t)mf * 16 * P.Kp + kw * 32);
  };

  f32x4 acc[2][4] = {};
  uint4 Acur[4], Anext[4] = {};
  loadG(0, S0);
  loadA(0, Acur);
  writeS(0, 0, S0);
  if (kt > 1) loadG(1, S1);
  if (kt > 2) loadG(2, S2);
  __syncthreads();
  int cur = 0;

  // step t: issue G(t+3) into Sload (its old tile G(t) already in LDS);
  //         MFMA on buf cur (tile t); write G(t+1) from Swrite into buf cur^1.
  auto step = [&](int t, uint4* Sload, uint4* Swrite) {
    if (t + 3 < kt) loadG(t + 3, Sload);
    if (t + 1 < kt) loadA(t + 1, Anext);
#pragma unroll
    for (int kw = 0; kw < 2; ++kw) {
      union { uint4 u; short8 s; } a0, a1;
      a0.u = Acur[0 * 2 + kw];
      a1.u = Acur[1 * 2 + kw];
#pragma unroll
      for (int nf = 0; nf < 4; ++nf) {
        union { uint4 u; short8 s; } bf;
        bf.u = *(const uint4*)&sh.g.db[cur][(wn * 64 + nf * 16 + c) * 144 + kw * 64 + g * 16];
        acc[0][nf] = __builtin_amdgcn_mfma_f32_16x16x32_bf16(a0.s, bf.s, acc[0][nf], 0, 0, 0);
        acc[1][nf] = __builtin_amdgcn_mfma_f32_16x16x32_bf16(a1.s, bf.s, acc[1][nf], 0, 0, 0);
      }
    }
    if (t + 1 < kt) writeS(cur ^ 1, t + 1, Swrite);
    __syncthreads();
    cur ^= 1;
#pragma unroll
    for (int i = 0; i < 4; ++i) Acur[i] = Anext[i];
  };
  for (int t = 0; t < kt;) {
    step(t, S0, S1);
    ++t;
    if (t >= kt) break;
    step(t, S1, S2);
    ++t;
    if (t >= kt) break;
    step(t, S2, S0);
    ++t;
  }

  // C-write (bf16 raw, round-to-nearest)
#pragma unroll
  for (int nf = 0; nf < 4; ++nf) {
    int n = n0 + wn * 64 + nf * 16 + c;
    unsigned short* yrow = P.Y + ((size_t)b * NPTS + n) * P.Ystride;
#pragma unroll
    for (int mf = 0; mf < 2; ++mf) {
      int mb = m0 + wm * 32 + mf * 16 + g * 4;
      if (mb < P.M)
        *(uint2*)(yrow + mb) =
            pack4(acc[mf][nf][0], acc[mf][nf][1], acc[mf][nf][2], acc[mf][nf][3]);
    }
  }
  // BN partials: slot = b*64 + nt*2 + wn (128 slots)
  int slot = b * 64 + nt * 2 + wn;
#pragma unroll
  for (int mf = 0; mf < 2; ++mf)
#pragma unroll
    for (int r = 0; r < 4; ++r) {
      float s = 0.f, q = 0.f;
#pragma unroll
      for (int nf = 0; nf < 4; ++nf) {
        float v = acc[mf][nf][r];
        s += v;
        q = fmaf(v, v, q);
      }
#pragma unroll
      for (int m = 1; m < 16; m <<= 1) {
        s += __shfl_xor(s, m, 64);
        q += __shfl_xor(q, m, 64);
      }
      int row = m0 + wm * 32 + mf * 16 + g * 4 + r;
      if (c == 0 && row < P.M) {
        P.psum[(size_t)row * 128 + slot] = s;
        P.psq[(size_t)row * 128 + slot] = q;
      }
    }
}

// ==================== BN finalize ====================
__global__ __launch_bounds__(128)
void bn_finalize(const float* __restrict__ psum, const float* __restrict__ psq,
                 const float* __restrict__ gamma, const float* __restrict__ beta,
                 float* __restrict__ a_, float* __restrict__ b_, float* __restrict__ f_) {
  int ch = blockIdx.x, t = threadIdx.x;
  float s = psum[(size_t)ch * 128 + t];
  float q = psq[(size_t)ch * 128 + t];
#pragma unroll
  for (int m = 1; m < 64; m <<= 1) {
    s += __shfl_xor(s, m, 64);
    q += __shfl_xor(q, m, 64);
  }
  __shared__ float ws[2][2];
  if ((t & 63) == 0) { ws[t >> 6][0] = s; ws[t >> 6][1] = q; }
  __syncthreads();
  if (t == 0) {
    float S = ws[0][0] + ws[1][0];
    float Q = ws[0][1] + ws[1][1];
    const float inv = 1.f / (float)(NB * NPTS);
    float mean = S * inv;
    float var = fmaxf(Q * inv - mean * mean, 0.f);
    float aa = rsqrtf(var + 1e-5f) * gamma[ch];
    a_[ch] = aa;
    b_[ch] = beta[ch] - mean * aa;
    if (f_) f_[ch] = 0.f;
  }
}

// ==================== out: BN+transpose z + xyz copy ====================
__global__ __launch_bounds__(256)
void out_final(const unsigned short* __restrict__ Y, const float* __restrict__ a_,
               const float* __restrict__ b_, const float* __restrict__ pc,
               float* __restrict__ out) {
  int bid = blockIdx.x;
  if (bid < 1024) {
    __shared__ float tile[32][33];
    int b = bid >> 9, r0 = bid & 511;
    int c0 = (r0 & 3) * 32, n0 = (r0 >> 2) * 32;
    int r = threadIdx.x >> 3, q = threadIdx.x & 7;
    uint2 v = *(const uint2*)(Y + ((size_t)b * NPTS + n0 + r) * 128 + c0 + q * 4);
    float4 aa = *(const float4*)(a_ + c0 + q * 4);
    float4 bb = *(const float4*)(b_ + c0 + q * 4);
    tile[r][q * 4 + 0] = fmaxf(bflo(v.x) * aa.x + bb.x, 0.f);
    tile[r][q * 4 + 1] = fmaxf(bfhi(v.x) * aa.y + bb.y, 0.f);
    tile[r][q * 4 + 2] = fmaxf(bflo(v.y) * aa.z + bb.z, 0.f);
    tile[r][q * 4 + 3] = fmaxf(bfhi(v.y) * aa.w + bb.w, 0.f);
    __syncthreads();
    float4 o = make_float4(tile[q * 4 + 0][r], tile[q * 4 + 1][r], tile[q * 4 + 2][r],
                           tile[q * 4 + 3][r]);
    float* z = out + (size_t)NB * NPTS * 3;
    *(float4*)(z + ((size_t)b * 128 + c0 + r) * NPTS + n0 + q * 4) = o;
  } else {
    int i = (bid - 1024) * 256 + threadIdx.x;
    ((float4*)out)[i] = ((const float4*)pc)[i];
  }
}

extern "C" void kernel_launch(void* const* d_in, const int* in_sizes, int n_in,
                              void* d_out, int out_size, void* d_ws, size_t ws_size,
                              hipStream_t stream) {
  (void)in_sizes; (void)n_in; (void)out_size; (void)ws_size;
  const float* pc    = (const float*)d_in[0];
  const float* h1    = (const float*)d_in[1];
  const float* h2    = (const float*)d_in[2];
  const float* dgw1  = (const float*)d_in[3];
  const float* dgg1  = (const float*)d_in[5];
  const float* dgbe1 = (const float*)d_in[6];
  const float* dgw2  = (const float*)d_in[7];
  const float* dgg2  = (const float*)d_in[9];
  const float* dgbe2 = (const float*)d_in[10];
  const float* dgw3  = (const float*)d_in[11];
  const float* dgg3  = (const float*)d_in[13];
  const float* dgbe3 = (const float*)d_in[14];
  const float* ew1   = (const float*)d_in[15];
  const float* eb1   = (const float*)d_in[16];
  const float* ew2   = (const float*)d_in[17];
  const float* eb2   = (const float*)d_in[18];
  const float* w1    = (const float*)d_in[19];
  const float* g1    = (const float*)d_in[21];
  const float* be1   = (const float*)d_in[22];
  const float* w2    = (const float*)d_in[23];
  const float* g2    = (const float*)d_in[25];
  const float* be2   = (const float*)d_in[26];
  const float* w3    = (const float*)d_in[27];
  const float* g3    = (const float*)d_in[29];
  const float* be3   = (const float*)d_in[30];
  float* out = (float*)d_out;

  // ---- workspace ----
  char* p = (char*)d_ws;
  auto take = [&](size_t bytes) { char* r = p; p += (bytes + 255) & ~(size_t)255; return r; };
  unsigned int* mx = (unsigned int*)take(64);
  unsigned short* h2t = (unsigned short*)take((size_t)NB * NPTS * 1024 * 2);
  unsigned short* Zt  = (unsigned short*)take((size_t)NB * NPTS * 192 * 2);
  unsigned short* wp1 = (unsigned short*)take((size_t)256 * 1024 * 2);
  unsigned short* wp2 = (unsigned short*)take((size_t)64 * 256 * 2);
  unsigned short* wp3 = (unsigned short*)take((size_t)64 * 64 * 2);
  unsigned short* wp4 = (unsigned short*)take((size_t)512 * 192 * 2);
  unsigned short* wp5 = (unsigned short*)take((size_t)256 * 512 * 2);
  unsigned short* wp6 = (unsigned short*)take((size_t)128 * 256 * 2);
  unsigned short* yA  = (unsigned short*)take((size_t)NB * NPTS * 256 * 2);
  unsigned short* yB  = (unsigned short*)take((size_t)NB * NPTS * 512 * 2);
  float* psum = (float*)take((size_t)512 * 128 * 4);
  float* psq  = (float*)take((size_t)512 * 128 * 4);
  float* a1 = (float*)take(512 * 4); float* b1 = (float*)take(512 * 4);
  float* a2 = (float*)take(512 * 4); float* b2 = (float*)take(512 * 4);
  float* aZ = (float*)take(512 * 4); float* bZ = (float*)take(512 * 4);
  float* fZ = (float*)take(512 * 4);
  float* a4 = (float*)take(512 * 4); float* b4 = (float*)take(512 * 4);
  float* a5 = (float*)take(512 * 4); float* b5 = (float*)take(512 * 4);
  float* a6 = (float*)take(512 * 4); float* b6 = (float*)take(512 * 4);
  float* f0 = (float*)take(512 * 4);
  float* part = (float*)take((size_t)NB * 4 * 10 * NPTS * 4);

  hipMemsetAsync(mx, 0, 64, stream);

  PrepP PP;
  PP.h2 = h2; PP.h1 = h1; PP.pc = pc;
  PP.wsrc[0] = dgw1; PP.wsrc[1] = dgw2; PP.wsrc[2] = dgw3;
  PP.wsrc[3] = w1;   PP.wsrc[4] = w2;   PP.wsrc[5] = w3;
  PP.wdst[0] = wp1; PP.wdst[1] = wp2; PP.wdst[2] = wp3;
  PP.wdst[3] = wp4; PP.wdst[4] = wp5; PP.wdst[5] = wp6;
  PP.h2t = h2t; PP.Zt = Zt;
  PP.aZ = aZ; PP.bZ = bZ; PP.fZ = fZ; PP.f0 = f0;
  PP.mx = mx;
  prep_maxd2<<<3617, 256, 0, stream>>>(PP);

  EigP EP = {pc, mx, part, ew1, eb1, ew2, eb2, Zt};

  // L1 + eigs_partial co-scheduled
  GemmP L1 = {wp1, h2t, nullptr, nullptr, nullptr, yA, 256, psum, psq, 256, 1024};
  gemm_k<0, 1><<<dim3(32, 4, NB + 8), 256, 0, stream>>>(L1, EP);
  bn_finalize<<<256, 128, 0, stream>>>(psum, psq, dgg1, dgbe1, a1, b1, nullptr);

  // L2 + eigs_finalize co-scheduled
  GemmP L2 = {wp2, yA, a1, b1, f0, yB, 64, psum, psq, 64, 256};
  gemm_k<1, 2><<<dim3(32, 1, NB + 1), 256, 0, stream>>>(L2, EP);
  bn_finalize<<<64, 128, 0, stream>>>(psum, psq, dgg2, dgbe2, a2, b2, nullptr);

  GemmP L3 = {wp3, yB, a2, b2, f0, Zt + 128, 192, psum, psq, 32, 64};
  gemm_k<1, 0><<<dim3(32, 1, NB), 256, 0, stream>>>(L3, EP);
  bn_finalize<<<32, 128, 0, stream>>>(psum, psq, dgg3, dgbe3, aZ + 128, bZ + 128, fZ + 128);

  // head chain
  GemmP L4 = {wp4, Zt, aZ, bZ, fZ, yB, 512, psum, psq, 512, 192};
  gemm_k<1, 0><<<dim3(32, 8, NB), 256, 0, stream>>>(L4, EP);
  bn_finalize<<<512, 128, 0, stream>>>(psum, psq, g1, be1, a4, b4, nullptr);

  GemmP L5 = {wp5, yB, a4, b4, f0, yA, 256, psum, psq, 256, 512};
  gemm_k<1, 0><<<dim3(32, 4, NB), 256, 0, stream>>>(L5, EP);
  bn_finalize<<<256, 128, 0, stream>>>(psum, psq, g2, be2, a5, b5, nullptr);

  GemmP L6 = {wp6, yA, a5, b5, f0, yB, 128, psum, psq, 128, 256};
  gemm_k<1, 0><<<dim3(32, 2, NB), 256, 0, stream>>>(L6, EP);
  bn_finalize<<<128, 128, 0, stream>>>(psum, psq, g3, be3, a6, b6, nullptr);

  out_final<<<1048, 256, 0, stream>>>(yB, a6, b6, pc, out);
}